// Round 1
// baseline (2005.389 us; speedup 1.0000x reference)
//
#include <hip/hip_runtime.h>

#define F 64

// ---------------- degree count (int atomics) ----------------
__global__ __launch_bounds__(256) void k_deg(const int* __restrict__ dst,
                                             int* __restrict__ deg, int E) {
    int e = blockIdx.x * 256 + threadIdx.x;
    if (e < E) atomicAdd(&deg[dst[e]], 1);
}

// ---------------- dinv = rsqrt(deg + 1) in place ----------------
__global__ __launch_bounds__(256) void k_dinv(float* __restrict__ buf, int N) {
    int i = blockIdx.x * 256 + threadIdx.x;
    if (i < N) {
        int d = ((const int*)buf)[i];          // self-loop adds +1
        buf[i] = rsqrtf((float)(d + 1));
    }
}

// ---------------- hs = (X @ W) * dinv[row] ----------------
// 64x64 output tile per block, 256 threads, 4x4 register tile per thread.
__global__ __launch_bounds__(256) void k_gemm_scale(const float* __restrict__ X,
                                                    const float* __restrict__ W,
                                                    const float* __restrict__ dinv,
                                                    float* __restrict__ out, int N) {
    __shared__ float Ws[64 * 64];
    __shared__ float Xs[64 * 65];              // +1 pad breaks bank aliasing
    const int t = threadIdx.x;
    const int row0 = blockIdx.x * 64;

    for (int i = t; i < 64 * 64; i += 256) Ws[i] = W[i];
    for (int i = t; i < 64 * 64; i += 256) {
        int r = i >> 6, c = i & 63;
        int gr = row0 + r;
        Xs[r * 65 + c] = (gr < N) ? X[(size_t)gr * F + c] : 0.f;
    }
    __syncthreads();

    const int cg = (t & 15) * 4;               // 16 col-groups of 4
    const int rg = (t >> 4) * 4;               // 16 row-groups of 4
    float acc[4][4] = {};
#pragma unroll
    for (int k = 0; k < 64; ++k) {
        float4 w4 = *(const float4*)&Ws[k * 64 + cg];
        float a0 = Xs[(rg + 0) * 65 + k];
        float a1 = Xs[(rg + 1) * 65 + k];
        float a2 = Xs[(rg + 2) * 65 + k];
        float a3 = Xs[(rg + 3) * 65 + k];
        acc[0][0] += a0 * w4.x; acc[0][1] += a0 * w4.y; acc[0][2] += a0 * w4.z; acc[0][3] += a0 * w4.w;
        acc[1][0] += a1 * w4.x; acc[1][1] += a1 * w4.y; acc[1][2] += a1 * w4.z; acc[1][3] += a1 * w4.w;
        acc[2][0] += a2 * w4.x; acc[2][1] += a2 * w4.y; acc[2][2] += a2 * w4.z; acc[2][3] += a2 * w4.w;
        acc[3][0] += a3 * w4.x; acc[3][1] += a3 * w4.y; acc[3][2] += a3 * w4.z; acc[3][3] += a3 * w4.w;
    }
#pragma unroll
    for (int j = 0; j < 4; ++j) {
        int gr = row0 + rg + j;
        if (gr < N) {
            float s = dinv[gr];
            float4 v = make_float4(acc[j][0] * s, acc[j][1] * s, acc[j][2] * s, acc[j][3] * s);
            *(float4*)&out[(size_t)gr * F + cg] = v;
        }
    }
}

// ---------------- scatter: acc[dst] += hs[src]  (16 lanes/edge) ----------------
__global__ __launch_bounds__(256) void k_scatter(const float* __restrict__ hs,
                                                 const int* __restrict__ src,
                                                 const int* __restrict__ dst,
                                                 float* __restrict__ acc, int E) {
    long long gid = (long long)blockIdx.x * 256 + threadIdx.x;
    int e = (int)(gid >> 4);
    int q = (int)(gid & 15);
    if (e >= E) return;
    int s = src[e];
    int d = dst[e];
    float4 v = *(const float4*)&hs[(size_t)s * F + q * 4];
    float* p = &acc[(size_t)d * F + q * 4];
    unsafeAtomicAdd(p + 0, v.x);
    unsafeAtomicAdd(p + 1, v.y);
    unsafeAtomicAdd(p + 2, v.z);
    unsafeAtomicAdd(p + 3, v.w);
}

// ---------------- out = (acc + hs) * dinv[row] + b  [, relu] ----------------
__global__ __launch_bounds__(256) void k_combine(const float* __restrict__ acc,
                                                 const float* __restrict__ hs,
                                                 const float* __restrict__ dinv,
                                                 const float* __restrict__ b,
                                                 float* __restrict__ out,
                                                 int N, int do_relu) {
    int i = blockIdx.x * 256 + threadIdx.x;    // one float4 per thread
    int total = N * (F / 4);
    if (i >= total) return;
    int r = i >> 4;
    int q = i & 15;
    float s = dinv[r];
    float4 a = *(const float4*)&acc[(size_t)i * 4];
    float4 h = *(const float4*)&hs[(size_t)i * 4];
    float4 bb = *(const float4*)&b[q * 4];
    float4 o;
    o.x = (a.x + h.x) * s + bb.x;
    o.y = (a.y + h.y) * s + bb.y;
    o.z = (a.z + h.z) * s + bb.z;
    o.w = (a.w + h.w) * s + bb.w;
    if (do_relu) {
        o.x = fmaxf(o.x, 0.f); o.y = fmaxf(o.y, 0.f);
        o.z = fmaxf(o.z, 0.f); o.w = fmaxf(o.w, 0.f);
    }
    *(float4*)&out[(size_t)i * 4] = o;
}

extern "C" void kernel_launch(void* const* d_in, const int* in_sizes, int n_in,
                              void* d_out, int out_size, void* d_ws, size_t ws_size,
                              hipStream_t stream) {
    const float* x  = (const float*)d_in[0];
    const int*   ei = (const int*)d_in[1];
    const float* W1 = (const float*)d_in[2];
    const float* b1 = (const float*)d_in[3];
    const float* W2 = (const float*)d_in[4];
    const float* b2 = (const float*)d_in[5];
    float* out = (float*)d_out;

    const int N = in_sizes[0] / F;
    const int E = in_sizes[1] / 2;
    const int* src = ei;
    const int* dst = ei + E;

    char* ws = (char*)d_ws;
    size_t nodeBytes = ((size_t)N * 4 + 255) & ~(size_t)255;
    size_t featBytes = (size_t)N * F * 4;
    float* dinv = (float*)(ws);
    float* hs   = (float*)(ws + nodeBytes);
    float* acc  = (float*)(ws + nodeBytes + featBytes);

    const int gDeg   = (E + 255) / 256;
    const int gNode  = (N + 255) / 256;
    const int gGemm  = (N + 63) / 64;
    const int gScat  = (int)(((long long)E * 16 + 255) / 256);
    const int gComb  = (N * (F / 4) + 255) / 256;

    // degree -> dinv (graph-invariant, compute once)
    hipMemsetAsync(dinv, 0, (size_t)N * 4, stream);
    k_deg<<<gDeg, 256, 0, stream>>>(dst, (int*)dinv, E);
    k_dinv<<<gNode, 256, 0, stream>>>(dinv, N);

    // ---- layer 1 ----
    k_gemm_scale<<<gGemm, 256, 0, stream>>>(x, W1, dinv, hs, N);
    hipMemsetAsync(acc, 0, featBytes, stream);
    k_scatter<<<gScat, 256, 0, stream>>>(hs, src, dst, acc, E);
    k_combine<<<gComb, 256, 0, stream>>>(acc, hs, dinv, b1, acc, N, 1);  // in-place, +relu

    // ---- layer 2 ----
    k_gemm_scale<<<gGemm, 256, 0, stream>>>(acc, W2, dinv, hs, N);
    hipMemsetAsync(acc, 0, featBytes, stream);
    k_scatter<<<gScat, 256, 0, stream>>>(hs, src, dst, acc, E);
    k_combine<<<gComb, 256, 0, stream>>>(acc, hs, dinv, b2, out, N, 0);
}

// Round 2
// 697.488 us; speedup vs baseline: 2.8752x; 2.8752x over previous
//
#include <hip/hip_runtime.h>

#define F 64

// ---------------- degree count (int atomics) ----------------
__global__ __launch_bounds__(256) void k_deg(const int* __restrict__ dst,
                                             int* __restrict__ deg, int E) {
    int e = blockIdx.x * 256 + threadIdx.x;
    if (e < E) atomicAdd(&deg[dst[e]], 1);
}

// ---------------- single-block exclusive scan: deg -> rowptr, cursor, dinv ----------------
__global__ __launch_bounds__(1024) void k_scan(const int* __restrict__ deg,
                                               int* __restrict__ rowptr,
                                               int* __restrict__ cursor,
                                               float* __restrict__ dinv, int N) {
    __shared__ int sums[1024];
    const int t = threadIdx.x;
    const int chunk = (N + 1023) / 1024;
    const int lo = t * chunk;
    const int hi = min(N, lo + chunk);
    int s = 0;
    for (int i = lo; i < hi; ++i) s += deg[i];
    sums[t] = s;
    __syncthreads();
    // Hillis-Steele inclusive scan over 1024 partials
    for (int off = 1; off < 1024; off <<= 1) {
        int v = (t >= off) ? sums[t - off] : 0;
        __syncthreads();
        sums[t] += v;
        __syncthreads();
    }
    int base = (t > 0) ? sums[t - 1] : 0;
    for (int i = lo; i < hi; ++i) {
        rowptr[i] = base;
        cursor[i] = base;
        int d = deg[i];
        dinv[i] = rsqrtf((float)(d + 1));   // +1 = self loop
        base += d;
    }
    if (t == 1023) rowptr[N] = base;        // = E
}

// ---------------- CSR fill (int atomics on cursor) ----------------
__global__ __launch_bounds__(256) void k_fill(const int* __restrict__ src,
                                              const int* __restrict__ dst,
                                              int* __restrict__ cursor,
                                              int* __restrict__ csr, int E) {
    int e = blockIdx.x * 256 + threadIdx.x;
    if (e < E) {
        int p = atomicAdd(&cursor[dst[e]], 1);
        csr[p] = src[e];
    }
}

// ---------------- hs = (X @ W) * dinv[row] ----------------
__global__ __launch_bounds__(256) void k_gemm_scale(const float* __restrict__ X,
                                                    const float* __restrict__ W,
                                                    const float* __restrict__ dinv,
                                                    float* __restrict__ out, int N) {
    __shared__ float Ws[64 * 64];
    __shared__ float Xs[64 * 65];
    const int t = threadIdx.x;
    const int row0 = blockIdx.x * 64;

    for (int i = t; i < 64 * 64; i += 256) Ws[i] = W[i];
    for (int i = t; i < 64 * 64; i += 256) {
        int r = i >> 6, c = i & 63;
        int gr = row0 + r;
        Xs[r * 65 + c] = (gr < N) ? X[(size_t)gr * F + c] : 0.f;
    }
    __syncthreads();

    const int cg = (t & 15) * 4;
    const int rg = (t >> 4) * 4;
    float acc[4][4] = {};
#pragma unroll
    for (int k = 0; k < 64; ++k) {
        float4 w4 = *(const float4*)&Ws[k * 64 + cg];
        float a0 = Xs[(rg + 0) * 65 + k];
        float a1 = Xs[(rg + 1) * 65 + k];
        float a2 = Xs[(rg + 2) * 65 + k];
        float a3 = Xs[(rg + 3) * 65 + k];
        acc[0][0] += a0 * w4.x; acc[0][1] += a0 * w4.y; acc[0][2] += a0 * w4.z; acc[0][3] += a0 * w4.w;
        acc[1][0] += a1 * w4.x; acc[1][1] += a1 * w4.y; acc[1][2] += a1 * w4.z; acc[1][3] += a1 * w4.w;
        acc[2][0] += a2 * w4.x; acc[2][1] += a2 * w4.y; acc[2][2] += a2 * w4.z; acc[2][3] += a2 * w4.w;
        acc[3][0] += a3 * w4.x; acc[3][1] += a3 * w4.y; acc[3][2] += a3 * w4.z; acc[3][3] += a3 * w4.w;
    }
#pragma unroll
    for (int j = 0; j < 4; ++j) {
        int gr = row0 + rg + j;
        if (gr < N) {
            float s = dinv[gr];
            float4 v = make_float4(acc[j][0] * s, acc[j][1] * s, acc[j][2] * s, acc[j][3] * s);
            *(float4*)&out[(size_t)gr * F + cg] = v;
        }
    }
}

// ---------------- fused aggregate: out = (sum_{src in CSR} hs[src] + hs[i]) * dinv[i] + b ----------------
// 16 lanes per node, each lane owns a float4 column slice. Index prefetch via __shfl.
__global__ __launch_bounds__(256) void k_agg(const float* __restrict__ hs,
                                             const int* __restrict__ rowptr,
                                             const int* __restrict__ csr,
                                             const float* __restrict__ dinv,
                                             const float* __restrict__ b,
                                             float* __restrict__ out,
                                             int N, int do_relu) {
    int gid = blockIdx.x * 256 + threadIdx.x;
    int node = gid >> 4;
    int lane = gid & 15;
    if (node >= N) return;
    int beg = rowptr[node];
    int end = rowptr[node + 1];
    int q = lane * 4;

    float4 acc = *(const float4*)&hs[(size_t)node * F + q];   // self loop
    for (int base = beg; base < end; base += 16) {
        int myj = base + lane;
        int myidx = (myj < end) ? csr[myj] : 0;               // 16 indices fetched at once
        int cnt = min(16, end - base);
        for (int k = 0; k < cnt; ++k) {
            int s = __shfl(myidx, k, 16);
            float4 v = *(const float4*)&hs[(size_t)s * F + q];
            acc.x += v.x; acc.y += v.y; acc.z += v.z; acc.w += v.w;
        }
    }

    float sc = dinv[node];
    float4 bb = *(const float4*)&b[q];
    float4 o = make_float4(acc.x * sc + bb.x, acc.y * sc + bb.y,
                           acc.z * sc + bb.z, acc.w * sc + bb.w);
    if (do_relu) {
        o.x = fmaxf(o.x, 0.f); o.y = fmaxf(o.y, 0.f);
        o.z = fmaxf(o.z, 0.f); o.w = fmaxf(o.w, 0.f);
    }
    *(float4*)&out[(size_t)node * F + q] = o;
}

extern "C" void kernel_launch(void* const* d_in, const int* in_sizes, int n_in,
                              void* d_out, int out_size, void* d_ws, size_t ws_size,
                              hipStream_t stream) {
    const float* x  = (const float*)d_in[0];
    const int*   ei = (const int*)d_in[1];
    const float* W1 = (const float*)d_in[2];
    const float* b1 = (const float*)d_in[3];
    const float* W2 = (const float*)d_in[4];
    const float* b2 = (const float*)d_in[5];
    float* out = (float*)d_out;

    const int N = in_sizes[0] / F;
    const int E = in_sizes[1] / 2;
    const int* src = ei;
    const int* dst = ei + E;

    // workspace layout (~31 MB): deg | rowptr | cursor | dinv | csr | hs
    char* ws = (char*)d_ws;
    size_t nodeInts = ((size_t)(N + 1) * 4 + 255) & ~(size_t)255;
    int*   deg    = (int*)(ws);
    int*   rowptr = (int*)(ws + nodeInts);
    int*   cursor = (int*)(ws + 2 * nodeInts);
    float* dinv   = (float*)(ws + 3 * nodeInts);
    int*   csr    = (int*)(ws + 4 * nodeInts);
    float* hs     = (float*)(ws + 4 * nodeInts + (((size_t)E * 4 + 255) & ~(size_t)255));

    const int gE    = (E + 255) / 256;
    const int gGemm = (N + 63) / 64;
    const int gAgg  = (int)(((long long)N * 16 + 255) / 256);

    // ---- CSR build (per launch; graph-invariant math folded into dinv) ----
    hipMemsetAsync(deg, 0, (size_t)N * 4, stream);
    k_deg<<<gE, 256, 0, stream>>>(dst, deg, E);
    k_scan<<<1, 1024, 0, stream>>>(deg, rowptr, cursor, dinv, N);
    k_fill<<<gE, 256, 0, stream>>>(src, dst, cursor, csr, E);

    // ---- layer 1 (act1 lives in d_out as scratch) ----
    k_gemm_scale<<<gGemm, 256, 0, stream>>>(x, W1, dinv, hs, N);
    k_agg<<<gAgg, 256, 0, stream>>>(hs, rowptr, csr, dinv, b1, out, N, 1);

    // ---- layer 2 ----
    k_gemm_scale<<<gGemm, 256, 0, stream>>>(out, W2, dinv, hs, N);
    k_agg<<<gAgg, 256, 0, stream>>>(hs, rowptr, csr, dinv, b2, out, N, 0);
}

// Round 3
// 418.933 us; speedup vs baseline: 4.7869x; 1.6649x over previous
//
#include <hip/hip_runtime.h>

#define F 64

// ---------------- degree count (int atomics) ----------------
__global__ __launch_bounds__(256) void k_deg(const int* __restrict__ dst,
                                             int* __restrict__ deg, int E) {
    int e = blockIdx.x * 256 + threadIdx.x;
    if (e < E) atomicAdd(&deg[dst[e]], 1);
}

// ---------------- scan stage 1: per-block (1024 elems) partial sums ----------------
__global__ __launch_bounds__(256) void k_part(const int* __restrict__ deg,
                                              int* __restrict__ part, int N) {
    __shared__ int sdata[256];
    const int t = threadIdx.x;
    const int base = blockIdx.x * 1024 + t * 4;
    int s = 0;
    if (base + 3 < N) {
        int4 d = *(const int4*)&deg[base];
        s = d.x + d.y + d.z + d.w;
    } else {
#pragma unroll
        for (int j = 0; j < 4; ++j) if (base + j < N) s += deg[base + j];
    }
    sdata[t] = s;
    __syncthreads();
    for (int off = 128; off > 0; off >>= 1) {
        if (t < off) sdata[t] += sdata[t + off];
        __syncthreads();
    }
    if (t == 0) part[blockIdx.x] = sdata[0];
}

// ---------------- scan stage 2: exclusive scan of block partials (1 small block) ----------------
__global__ __launch_bounds__(256) void k_scanp(int* __restrict__ part,
                                               int* __restrict__ rowptrN, int nb) {
    __shared__ int sums[256];
    const int t = threadIdx.x;
    const int chunk = (nb + 255) / 256;
    const int lo = t * chunk;
    const int hi = min(nb, lo + chunk);
    int s = 0;
    for (int i = lo; i < hi; ++i) s += part[i];
    sums[t] = s;
    __syncthreads();
    for (int off = 1; off < 256; off <<= 1) {
        int v = (t >= off) ? sums[t - off] : 0;
        __syncthreads();
        sums[t] += v;
        __syncthreads();
    }
    int base = (t > 0) ? sums[t - 1] : 0;
    for (int i = lo; i < hi; ++i) {
        int d = part[i];
        part[i] = base;          // becomes exclusive block offset
        base += d;
    }
    if (t == 255) *rowptrN = sums[255];   // rowptr[N] = E
}

// ---------------- scan stage 3: emit rowptr/cursor/dinv ----------------
__global__ __launch_bounds__(256) void k_emit(const int* __restrict__ deg,
                                              const int* __restrict__ part,
                                              int* __restrict__ rowptr,
                                              int* __restrict__ cursor,
                                              float* __restrict__ dinv, int N) {
    __shared__ int sums[256];
    const int t = threadIdx.x;
    const int base = blockIdx.x * 1024 + t * 4;
    int d0 = 0, d1 = 0, d2 = 0, d3 = 0;
    if (base + 3 < N) {
        int4 d = *(const int4*)&deg[base];
        d0 = d.x; d1 = d.y; d2 = d.z; d3 = d.w;
    } else {
        if (base + 0 < N) d0 = deg[base + 0];
        if (base + 1 < N) d1 = deg[base + 1];
        if (base + 2 < N) d2 = deg[base + 2];
        if (base + 3 < N) d3 = deg[base + 3];
    }
    int tot = d0 + d1 + d2 + d3;
    sums[t] = tot;
    __syncthreads();
    for (int off = 1; off < 256; off <<= 1) {
        int v = (t >= off) ? sums[t - off] : 0;
        __syncthreads();
        sums[t] += v;
        __syncthreads();
    }
    int off = part[blockIdx.x] + sums[t] - tot;   // global exclusive offset for elem base+0
    int e0 = off, e1 = off + d0, e2 = e1 + d1, e3 = e2 + d2;
    if (base + 3 < N) {
        *(int4*)&rowptr[base] = make_int4(e0, e1, e2, e3);
        *(int4*)&cursor[base] = make_int4(e0, e1, e2, e3);
        *(float4*)&dinv[base] = make_float4(rsqrtf((float)(d0 + 1)), rsqrtf((float)(d1 + 1)),
                                            rsqrtf((float)(d2 + 1)), rsqrtf((float)(d3 + 1)));
    } else {
        int ee[4] = {e0, e1, e2, e3};
        int dd[4] = {d0, d1, d2, d3};
        for (int j = 0; j < 4; ++j) if (base + j < N) {
            rowptr[base + j] = ee[j];
            cursor[base + j] = ee[j];
            dinv[base + j] = rsqrtf((float)(dd[j] + 1));
        }
    }
}

// ---------------- CSR fill (int atomics on cursor) ----------------
__global__ __launch_bounds__(256) void k_fill(const int* __restrict__ src,
                                              const int* __restrict__ dst,
                                              int* __restrict__ cursor,
                                              int* __restrict__ csr, int E) {
    int e = blockIdx.x * 256 + threadIdx.x;
    if (e < E) {
        int p = atomicAdd(&cursor[dst[e]], 1);
        csr[p] = src[e];
    }
}

// ---------------- hs = (X @ W) * dinv[row] ----------------
__global__ __launch_bounds__(256) void k_gemm_scale(const float* __restrict__ X,
                                                    const float* __restrict__ W,
                                                    const float* __restrict__ dinv,
                                                    float* __restrict__ out, int N) {
    __shared__ float Ws[64 * 64];
    __shared__ float Xs[64 * 65];
    const int t = threadIdx.x;
    const int row0 = blockIdx.x * 64;

    for (int i = t; i < 64 * 64; i += 256) Ws[i] = W[i];
    for (int i = t; i < 64 * 64; i += 256) {
        int r = i >> 6, c = i & 63;
        int gr = row0 + r;
        Xs[r * 65 + c] = (gr < N) ? X[(size_t)gr * F + c] : 0.f;
    }
    __syncthreads();

    const int cg = (t & 15) * 4;
    const int rg = (t >> 4) * 4;
    float acc[4][4] = {};
#pragma unroll
    for (int k = 0; k < 64; ++k) {
        float4 w4 = *(const float4*)&Ws[k * 64 + cg];
        float a0 = Xs[(rg + 0) * 65 + k];
        float a1 = Xs[(rg + 1) * 65 + k];
        float a2 = Xs[(rg + 2) * 65 + k];
        float a3 = Xs[(rg + 3) * 65 + k];
        acc[0][0] += a0 * w4.x; acc[0][1] += a0 * w4.y; acc[0][2] += a0 * w4.z; acc[0][3] += a0 * w4.w;
        acc[1][0] += a1 * w4.x; acc[1][1] += a1 * w4.y; acc[1][2] += a1 * w4.z; acc[1][3] += a1 * w4.w;
        acc[2][0] += a2 * w4.x; acc[2][1] += a2 * w4.y; acc[2][2] += a2 * w4.z; acc[2][3] += a2 * w4.w;
        acc[3][0] += a3 * w4.x; acc[3][1] += a3 * w4.y; acc[3][2] += a3 * w4.z; acc[3][3] += a3 * w4.w;
    }
#pragma unroll
    for (int j = 0; j < 4; ++j) {
        int gr = row0 + rg + j;
        if (gr < N) {
            float s = dinv[gr];
            float4 v = make_float4(acc[j][0] * s, acc[j][1] * s, acc[j][2] * s, acc[j][3] * s);
            *(float4*)&out[(size_t)gr * F + cg] = v;
        }
    }
}

// ---------------- fused aggregate: out = (sum_{src in CSR} hs[src] + hs[i]) * dinv[i] + b ----------------
__global__ __launch_bounds__(256) void k_agg(const float* __restrict__ hs,
                                             const int* __restrict__ rowptr,
                                             const int* __restrict__ csr,
                                             const float* __restrict__ dinv,
                                             const float* __restrict__ b,
                                             float* __restrict__ out,
                                             int N, int do_relu) {
    int gid = blockIdx.x * 256 + threadIdx.x;
    int node = gid >> 4;
    int lane = gid & 15;
    if (node >= N) return;
    int beg = rowptr[node];
    int end = rowptr[node + 1];
    int q = lane * 4;

    float4 acc = *(const float4*)&hs[(size_t)node * F + q];   // self loop
    for (int base = beg; base < end; base += 16) {
        int myj = base + lane;
        int myidx = (myj < end) ? csr[myj] : 0;
        int cnt = min(16, end - base);
        for (int k = 0; k < cnt; ++k) {
            int s = __shfl(myidx, k, 16);
            float4 v = *(const float4*)&hs[(size_t)s * F + q];
            acc.x += v.x; acc.y += v.y; acc.z += v.z; acc.w += v.w;
        }
    }

    float sc = dinv[node];
    float4 bb = *(const float4*)&b[q];
    float4 o = make_float4(acc.x * sc + bb.x, acc.y * sc + bb.y,
                           acc.z * sc + bb.z, acc.w * sc + bb.w);
    if (do_relu) {
        o.x = fmaxf(o.x, 0.f); o.y = fmaxf(o.y, 0.f);
        o.z = fmaxf(o.z, 0.f); o.w = fmaxf(o.w, 0.f);
    }
    *(float4*)&out[(size_t)node * F + q] = o;
}

extern "C" void kernel_launch(void* const* d_in, const int* in_sizes, int n_in,
                              void* d_out, int out_size, void* d_ws, size_t ws_size,
                              hipStream_t stream) {
    const float* x  = (const float*)d_in[0];
    const int*   ei = (const int*)d_in[1];
    const float* W1 = (const float*)d_in[2];
    const float* b1 = (const float*)d_in[3];
    const float* W2 = (const float*)d_in[4];
    const float* b2 = (const float*)d_in[5];
    float* out = (float*)d_out;

    const int N = in_sizes[0] / F;
    const int E = in_sizes[1] / 2;
    const int* src = ei;
    const int* dst = ei + E;
    const int nb = (N + 1023) / 1024;

    // workspace: deg | rowptr | cursor | dinv | part | csr | hs
    char* ws = (char*)d_ws;
    size_t nodeInts = ((size_t)(N + 1) * 4 + 255) & ~(size_t)255;
    size_t partInts = ((size_t)nb * 4 + 255) & ~(size_t)255;
    int*   deg    = (int*)(ws);
    int*   rowptr = (int*)(ws + nodeInts);
    int*   cursor = (int*)(ws + 2 * nodeInts);
    float* dinv   = (float*)(ws + 3 * nodeInts);
    int*   part   = (int*)(ws + 4 * nodeInts);
    int*   csr    = (int*)(ws + 4 * nodeInts + partInts);
    float* hs     = (float*)(ws + 4 * nodeInts + partInts + (((size_t)E * 4 + 255) & ~(size_t)255));

    const int gE    = (E + 255) / 256;
    const int gGemm = (N + 63) / 64;
    const int gAgg  = (int)(((long long)N * 16 + 255) / 256);

    // ---- CSR build ----
    hipMemsetAsync(deg, 0, (size_t)N * 4, stream);
    k_deg<<<gE, 256, 0, stream>>>(dst, deg, E);
    k_part<<<nb, 256, 0, stream>>>(deg, part, N);
    k_scanp<<<1, 256, 0, stream>>>(part, &rowptr[N], nb);
    k_emit<<<nb, 256, 0, stream>>>(deg, part, rowptr, cursor, dinv, N);
    k_fill<<<gE, 256, 0, stream>>>(src, dst, cursor, csr, E);

    // ---- layer 1 (act1 lives in d_out as scratch) ----
    k_gemm_scale<<<gGemm, 256, 0, stream>>>(x, W1, dinv, hs, N);
    k_agg<<<gAgg, 256, 0, stream>>>(hs, rowptr, csr, dinv, b1, out, N, 1);

    // ---- layer 2 ----
    k_gemm_scale<<<gGemm, 256, 0, stream>>>(out, W2, dinv, hs, N);
    k_agg<<<gAgg, 256, 0, stream>>>(hs, rowptr, csr, dinv, b2, out, N, 0);
}

// Round 4
// 316.491 us; speedup vs baseline: 6.3363x; 1.3237x over previous
//
#include <hip/hip_runtime.h>

#define F 64

// ---------------- degree count (int atomics) ----------------
__global__ __launch_bounds__(256) void k_deg(const int* __restrict__ dst,
                                             int* __restrict__ deg, int E) {
    int e = blockIdx.x * 256 + threadIdx.x;
    if (e < E) atomicAdd(&deg[dst[e]], 1);
}

// ---------------- scan stage 1: per-block (1024 elems) partial sums ----------------
__global__ __launch_bounds__(256) void k_part(const int* __restrict__ deg,
                                              int* __restrict__ part, int N) {
    __shared__ int sdata[256];
    const int t = threadIdx.x;
    const int base = blockIdx.x * 1024 + t * 4;
    int s = 0;
    if (base + 3 < N) {
        int4 d = *(const int4*)&deg[base];
        s = d.x + d.y + d.z + d.w;
    } else {
#pragma unroll
        for (int j = 0; j < 4; ++j) if (base + j < N) s += deg[base + j];
    }
    sdata[t] = s;
    __syncthreads();
    for (int off = 128; off > 0; off >>= 1) {
        if (t < off) sdata[t] += sdata[t + off];
        __syncthreads();
    }
    if (t == 0) part[blockIdx.x] = sdata[0];
}

// ---------------- scan stage 2: exclusive scan of block partials (1 small block) ----------------
__global__ __launch_bounds__(256) void k_scanp(int* __restrict__ part,
                                               int* __restrict__ rowptrN, int nb) {
    __shared__ int sums[256];
    const int t = threadIdx.x;
    const int chunk = (nb + 255) / 256;
    const int lo = t * chunk;
    const int hi = min(nb, lo + chunk);
    int s = 0;
    for (int i = lo; i < hi; ++i) s += part[i];
    sums[t] = s;
    __syncthreads();
    for (int off = 1; off < 256; off <<= 1) {
        int v = (t >= off) ? sums[t - off] : 0;
        __syncthreads();
        sums[t] += v;
        __syncthreads();
    }
    int base = (t > 0) ? sums[t - 1] : 0;
    for (int i = lo; i < hi; ++i) {
        int d = part[i];
        part[i] = base;          // becomes exclusive block offset
        base += d;
    }
    if (t == 255) *rowptrN = sums[255];   // rowptr[N] = E
}

// ---------------- scan stage 3: emit rowptr/cursor/dinv ----------------
__global__ __launch_bounds__(256) void k_emit(const int* __restrict__ deg,
                                              const int* __restrict__ part,
                                              int* __restrict__ rowptr,
                                              int* __restrict__ cursor,
                                              float* __restrict__ dinv, int N) {
    __shared__ int sums[256];
    const int t = threadIdx.x;
    const int base = blockIdx.x * 1024 + t * 4;
    int d0 = 0, d1 = 0, d2 = 0, d3 = 0;
    if (base + 3 < N) {
        int4 d = *(const int4*)&deg[base];
        d0 = d.x; d1 = d.y; d2 = d.z; d3 = d.w;
    } else {
        if (base + 0 < N) d0 = deg[base + 0];
        if (base + 1 < N) d1 = deg[base + 1];
        if (base + 2 < N) d2 = deg[base + 2];
        if (base + 3 < N) d3 = deg[base + 3];
    }
    int tot = d0 + d1 + d2 + d3;
    sums[t] = tot;
    __syncthreads();
    for (int off = 1; off < 256; off <<= 1) {
        int v = (t >= off) ? sums[t - off] : 0;
        __syncthreads();
        sums[t] += v;
        __syncthreads();
    }
    int off = part[blockIdx.x] + sums[t] - tot;   // global exclusive offset for elem base+0
    int e0 = off, e1 = off + d0, e2 = e1 + d1, e3 = e2 + d2;
    if (base + 3 < N) {
        *(int4*)&rowptr[base] = make_int4(e0, e1, e2, e3);
        *(int4*)&cursor[base] = make_int4(e0, e1, e2, e3);
        *(float4*)&dinv[base] = make_float4(rsqrtf((float)(d0 + 1)), rsqrtf((float)(d1 + 1)),
                                            rsqrtf((float)(d2 + 1)), rsqrtf((float)(d3 + 1)));
    } else {
        int ee[4] = {e0, e1, e2, e3};
        int dd[4] = {d0, d1, d2, d3};
        for (int j = 0; j < 4; ++j) if (base + j < N) {
            rowptr[base + j] = ee[j];
            cursor[base + j] = ee[j];
            dinv[base + j] = rsqrtf((float)(dd[j] + 1));
        }
    }
}

// ---------------- CSR fill (int atomics on cursor) ----------------
__global__ __launch_bounds__(256) void k_fill(const int* __restrict__ src,
                                              const int* __restrict__ dst,
                                              int* __restrict__ cursor,
                                              int* __restrict__ csr, int E) {
    int e = blockIdx.x * 256 + threadIdx.x;
    if (e < E) {
        int p = atomicAdd(&cursor[dst[e]], 1);
        csr[p] = src[e];
    }
}

// ---------------- hs = (X @ W) * dinv[row] ----------------
// 64x64 tile, 256 threads, 4x4/thread. Bounded unroll + b128 LDS reads;
// __launch_bounds__(256,4) caps VGPR<=128 so 4 blocks/CU fit (LDS 33.4KB).
__global__ __launch_bounds__(256, 4) void k_gemm_scale(const float* __restrict__ X,
                                                       const float* __restrict__ W,
                                                       const float* __restrict__ dinv,
                                                       float* __restrict__ out, int N) {
    __shared__ float Ws[64 * 64];      // 16 KB, row-major
    __shared__ float Xs[64 * 68];      // 17.4 KB, stride 68 keeps float4 align + bank spread
    const int t = threadIdx.x;
    const int row0 = blockIdx.x * 64;

    // stage W: 1024 float4 / 256 threads = 4 each
#pragma unroll
    for (int i = 0; i < 4; ++i) {
        int idx = t + i * 256;                   // float4 index
        *(float4*)&Ws[idx * 4] = *(const float4*)&W[idx * 4];
    }
    // stage X tile: 64 rows x 16 float4
#pragma unroll
    for (int i = 0; i < 4; ++i) {
        int idx = t + i * 256;
        int r = idx >> 4, c = (idx & 15) * 4;
        int gr = row0 + r;
        float4 v = make_float4(0.f, 0.f, 0.f, 0.f);
        if (gr < N) v = *(const float4*)&X[(size_t)gr * F + c];
        *(float4*)&Xs[r * 68 + c] = v;
    }
    __syncthreads();

    const int cg = (t & 15) * 4;
    const int rg = (t >> 4) * 4;
    float acc[4][4] = {};
#pragma unroll 2
    for (int k0 = 0; k0 < 64; k0 += 4) {
        float4 xr[4];
#pragma unroll
        for (int j = 0; j < 4; ++j) xr[j] = *(const float4*)&Xs[(rg + j) * 68 + k0];
#pragma unroll
        for (int kk = 0; kk < 4; ++kk) {
            float4 w4 = *(const float4*)&Ws[(k0 + kk) * 64 + cg];
            float a0 = ((const float*)&xr[0])[kk];
            float a1 = ((const float*)&xr[1])[kk];
            float a2 = ((const float*)&xr[2])[kk];
            float a3 = ((const float*)&xr[3])[kk];
            acc[0][0] += a0 * w4.x; acc[0][1] += a0 * w4.y; acc[0][2] += a0 * w4.z; acc[0][3] += a0 * w4.w;
            acc[1][0] += a1 * w4.x; acc[1][1] += a1 * w4.y; acc[1][2] += a1 * w4.z; acc[1][3] += a1 * w4.w;
            acc[2][0] += a2 * w4.x; acc[2][1] += a2 * w4.y; acc[2][2] += a2 * w4.z; acc[2][3] += a2 * w4.w;
            acc[3][0] += a3 * w4.x; acc[3][1] += a3 * w4.y; acc[3][2] += a3 * w4.z; acc[3][3] += a3 * w4.w;
        }
    }
#pragma unroll
    for (int j = 0; j < 4; ++j) {
        int gr = row0 + rg + j;
        if (gr < N) {
            float s = dinv[gr];
            float4 v = make_float4(acc[j][0] * s, acc[j][1] * s, acc[j][2] * s, acc[j][3] * s);
            *(float4*)&out[(size_t)gr * F + cg] = v;
        }
    }
}

// ---------------- fused aggregate: out = (sum_{src in CSR} hs[src] + hs[i]) * dinv[i] + b ----------------
__global__ __launch_bounds__(256) void k_agg(const float* __restrict__ hs,
                                             const int* __restrict__ rowptr,
                                             const int* __restrict__ csr,
                                             const float* __restrict__ dinv,
                                             const float* __restrict__ b,
                                             float* __restrict__ out,
                                             int N, int do_relu) {
    int gid = blockIdx.x * 256 + threadIdx.x;
    int node = gid >> 4;
    int lane = gid & 15;
    if (node >= N) return;
    int beg = rowptr[node];
    int end = rowptr[node + 1];
    int q = lane * 4;

    float4 acc = *(const float4*)&hs[(size_t)node * F + q];   // self loop
    for (int base = beg; base < end; base += 16) {
        int myj = base + lane;
        int myidx = (myj < end) ? csr[myj] : 0;
        int cnt = min(16, end - base);
        for (int k = 0; k < cnt; ++k) {
            int s = __shfl(myidx, k, 16);
            float4 v = *(const float4*)&hs[(size_t)s * F + q];
            acc.x += v.x; acc.y += v.y; acc.z += v.z; acc.w += v.w;
        }
    }

    float sc = dinv[node];
    float4 bb = *(const float4*)&b[q];
    float4 o = make_float4(acc.x * sc + bb.x, acc.y * sc + bb.y,
                           acc.z * sc + bb.z, acc.w * sc + bb.w);
    if (do_relu) {
        o.x = fmaxf(o.x, 0.f); o.y = fmaxf(o.y, 0.f);
        o.z = fmaxf(o.z, 0.f); o.w = fmaxf(o.w, 0.f);
    }
    *(float4*)&out[(size_t)node * F + q] = o;
}

extern "C" void kernel_launch(void* const* d_in, const int* in_sizes, int n_in,
                              void* d_out, int out_size, void* d_ws, size_t ws_size,
                              hipStream_t stream) {
    const float* x  = (const float*)d_in[0];
    const int*   ei = (const int*)d_in[1];
    const float* W1 = (const float*)d_in[2];
    const float* b1 = (const float*)d_in[3];
    const float* W2 = (const float*)d_in[4];
    const float* b2 = (const float*)d_in[5];
    float* out = (float*)d_out;

    const int N = in_sizes[0] / F;
    const int E = in_sizes[1] / 2;
    const int* src = ei;
    const int* dst = ei + E;
    const int nb = (N + 1023) / 1024;

    // workspace: deg | rowptr | cursor | dinv | part | csr | hs
    char* ws = (char*)d_ws;
    size_t nodeInts = ((size_t)(N + 1) * 4 + 255) & ~(size_t)255;
    size_t partInts = ((size_t)nb * 4 + 255) & ~(size_t)255;
    int*   deg    = (int*)(ws);
    int*   rowptr = (int*)(ws + nodeInts);
    int*   cursor = (int*)(ws + 2 * nodeInts);
    float* dinv   = (float*)(ws + 3 * nodeInts);
    int*   part   = (int*)(ws + 4 * nodeInts);
    int*   csr    = (int*)(ws + 4 * nodeInts + partInts);
    float* hs     = (float*)(ws + 4 * nodeInts + partInts + (((size_t)E * 4 + 255) & ~(size_t)255));

    const int gE    = (E + 255) / 256;
    const int gGemm = (N + 63) / 64;
    const int gAgg  = (int)(((long long)N * 16 + 255) / 256);

    // ---- CSR build ----
    hipMemsetAsync(deg, 0, (size_t)N * 4, stream);
    k_deg<<<gE, 256, 0, stream>>>(dst, deg, E);
    k_part<<<nb, 256, 0, stream>>>(deg, part, N);
    k_scanp<<<1, 256, 0, stream>>>(part, &rowptr[N], nb);
    k_emit<<<nb, 256, 0, stream>>>(deg, part, rowptr, cursor, dinv, N);
    k_fill<<<gE, 256, 0, stream>>>(src, dst, cursor, csr, E);

    // ---- layer 1 (act1 lives in d_out as scratch) ----
    k_gemm_scale<<<gGemm, 256, 0, stream>>>(x, W1, dinv, hs, N);
    k_agg<<<gAgg, 256, 0, stream>>>(hs, rowptr, csr, dinv, b1, out, N, 1);

    // ---- layer 2 ----
    k_gemm_scale<<<gGemm, 256, 0, stream>>>(out, W2, dinv, hs, N);
    k_agg<<<gAgg, 256, 0, stream>>>(hs, rowptr, csr, dinv, b2, out, N, 0);
}